// Round 4
// baseline (463.189 us; speedup 1.0000x reference)
//
#include <hip/hip_runtime.h>

#define EPS_BN 1e-5f

// Segment-parallel 3-NN + inverse-distance weights (unchanged from r3).
__global__ __launch_bounds__(512) void three_nn_par_kernel(
    const float* __restrict__ unknown,  // (B, Nu, 3)
    const float* __restrict__ known,    // (B, Nk, 3)
    int Nu, int Nk, int* __restrict__ idx, float* __restrict__ wgt)
{
    const int NSEG = 16;
    __shared__ float kl[3 * 1024];
    __shared__ float sd[NSEG][32][3];
    __shared__ int   si[NSEG][32][3];
    const int b = blockIdx.y;
    for (int i = threadIdx.x; i < Nk * 3; i += 512) kl[i] = known[(size_t)b * Nk * 3 + i];
    __syncthreads();
    const int u   = threadIdx.x & 31;
    const int seg = threadIdx.x >> 5;
    const int n   = blockIdx.x * 32 + u;
    const float* up = unknown + ((size_t)b * Nu + n) * 3;
    const float ux = up[0], uy = up[1], uz = up[2];
    float d0 = 1e30f, d1 = 1e30f, d2 = 1e30f;
    int i0 = 0, i1 = 0, i2 = 0;
    const int klo = seg * (Nk / NSEG), khi = klo + Nk / NSEG;
    for (int k = klo; k < khi; ++k) {
        float dx = __fsub_rn(ux, kl[3 * k + 0]);
        float dy = __fsub_rn(uy, kl[3 * k + 1]);
        float dz = __fsub_rn(uz, kl[3 * k + 2]);
        float d = __fadd_rn(__fadd_rn(__fmul_rn(dx, dx), __fmul_rn(dy, dy)), __fmul_rn(dz, dz));
        if (d < d0)      { d2 = d1; i2 = i1; d1 = d0; i1 = i0; d0 = d; i0 = k; }
        else if (d < d1) { d2 = d1; i2 = i1; d1 = d;  i1 = k; }
        else if (d < d2) { d2 = d;  i2 = k; }
    }
    sd[seg][u][0] = d0; sd[seg][u][1] = d1; sd[seg][u][2] = d2;
    si[seg][u][0] = i0; si[seg][u][1] = i1; si[seg][u][2] = i2;
    __syncthreads();
    if (threadIdx.x < 32) {
        float m0 = 1e30f, m1 = 1e30f, m2 = 1e30f;
        int j0 = 0, j1 = 0, j2 = 0;
        for (int s = 0; s < NSEG; ++s)
            for (int c = 0; c < 3; ++c) {
                float d = sd[s][u][c];
                int ii = si[s][u][c];
                if (d < m0)      { m2 = m1; j2 = j1; m1 = m0; j1 = j0; m0 = d; j0 = ii; }
                else if (d < m1) { m2 = m1; j2 = j1; m1 = d;  j1 = ii; }
                else if (d < m2) { m2 = d;  j2 = ii; }
            }
        float w0 = 1.f / (m0 + 1e-8f), w1 = 1.f / (m1 + 1e-8f), w2 = 1.f / (m2 + 1e-8f);
        float s = w0 + w1 + w2;
        size_t base = ((size_t)b * Nu + n) * 3;
        idx[base + 0] = j0; idx[base + 1] = j1; idx[base + 2] = j2;
        wgt[base + 0] = w0 / s; wgt[base + 1] = w1 / s; wgt[base + 2] = w2 / s;
    }
}

__global__ void interp_kernel(const float* __restrict__ feat,  // (NB, C, Ns)
    const int* __restrict__ idx, const float* __restrict__ wgt, // (B, Nu, 3)
    float* __restrict__ out,                                    // (NB, C, Nu)
    int C, int Ns, int Nu, int Q)
{
    int n = blockIdx.x * 256 + threadIdx.x;
    if (n >= Nu) return;
    int c = blockIdx.y;
    int nb = blockIdx.z;
    int b = nb / Q;
    size_t nnb = ((size_t)b * Nu + n) * 3;
    int j0 = idx[nnb], j1 = idx[nnb + 1], j2 = idx[nnb + 2];
    float w0 = wgt[nnb], w1 = wgt[nnb + 1], w2 = wgt[nnb + 2];
    const float* f = feat + ((size_t)nb * C + c) * Ns;
    out[((size_t)nb * C + c) * Nu + n] = w0 * f[j0] + w1 * f[j1] + w2 * f[j2];
}

// Barrier-free streaming conv+BN+ReLU.
// Block 256 threads; W^T (Ctot x OT) + folded scale/shift staged to LDS once;
// c-loop streams x from global (coalesced, VEC floats/lane) with a 2-deep
// register pipeline; no __syncthreads in the main loop.
template <int VEC, int OT>
__global__ __launch_bounds__(256) void conv_stream_kernel(
    const float* __restrict__ src0, int C0, int qdiv0,
    const float* __restrict__ src1, int C1, int qdiv1,
    const float* __restrict__ W, const float* __restrict__ bias,
    const float* __restrict__ bnp,
    float* __restrict__ outp, int O, int N, int relu)
{
    __shared__ float wlds[304 * OT];
    __shared__ float ssc[OT], ssh[OT];
    const int tid = threadIdx.x;
    const int oBase = blockIdx.y * OT;
    const int nb = blockIdx.z;
    const int Ctot = C0 + C1;

    for (int i = tid; i < Ctot * OT; i += 256) {
        int c = i / OT, ol = i % OT;
        int o = oBase + ol;
        wlds[i] = (o < O) ? W[(size_t)o * Ctot + c] : 0.f;
    }
    if (tid < OT) {
        int o = oBase + tid;
        float sc = 1.f, sh = 0.f, bv = (o < O) ? bias[o] : 0.f;
        if (bnp && o < O) {
            float g = bnp[o], be = bnp[O + o], m = bnp[2 * O + o], v = bnp[3 * O + o];
            sc = g * rsqrtf(v + EPS_BN);
            sh = be - m * sc;
        }
        ssc[tid] = sc;
        ssh[tid] = bv * sc + sh;   // y = acc*sc + (bias*sc + sh)
    }
    __syncthreads();

    const int n0 = (blockIdx.x * 256 + tid) * VEC;
    const float* s0 = src0 + (size_t)(nb / qdiv0) * C0 * N + n0;
    const float* s1 = (C1 > 0) ? (src1 + (size_t)(nb / qdiv1) * C1 * N + n0) : nullptr;

    float acc[OT][VEC];
#pragma unroll
    for (int ol = 0; ol < OT; ++ol)
#pragma unroll
        for (int j = 0; j < VEC; ++j) acc[ol][j] = 0.f;

    auto rowp = [&](int c) -> const float* {
        return (c < C0) ? (s0 + (size_t)c * N) : (s1 + (size_t)(c - C0) * N);
    };
    auto loadg = [&](float (&buf)[4][VEC], int cc) {
#pragma unroll
        for (int q = 0; q < 4; ++q) {
            const float* p = rowp(cc + q);
            if constexpr (VEC == 4) {
                float4 t = *reinterpret_cast<const float4*>(p);
                buf[q][0] = t.x; buf[q][1] = t.y; buf[q][2] = t.z; buf[q][3] = t.w;
            } else {
                buf[q][0] = *p;
            }
        }
    };
    auto cone = [&](int c, const float (&xs)[VEC]) {
        const float* wp = &wlds[c * OT];
#pragma unroll
        for (int g = 0; g < OT / 4; ++g) {
            float4 wv = *reinterpret_cast<const float4*>(wp + g * 4);
            float ww[4] = {wv.x, wv.y, wv.z, wv.w};
#pragma unroll
            for (int r = 0; r < 4; ++r)
#pragma unroll
                for (int j = 0; j < VEC; ++j)
                    acc[g * 4 + r][j] += ww[r] * xs[j];
        }
    };
    auto cgrp = [&](int cc, const float (&buf)[4][VEC]) {
#pragma unroll
        for (int q = 0; q < 4; ++q) cone(cc + q, buf[q]);
    };

    float xa[4][VEC], xb[4][VEC];
    int c = 0;
    if (Ctot >= 8) {
        loadg(xa, 0);
        for (; c + 8 <= Ctot; c += 8) {
            loadg(xb, c + 4);
            cgrp(c, xa);
            if (c + 12 <= Ctot) loadg(xa, c + 8);
            cgrp(c + 4, xb);
        }
        if (c + 4 <= Ctot) { cgrp(c, xa); c += 4; }
    }
    for (; c < Ctot; ++c) {
        float xs[VEC];
        const float* p = rowp(c);
        if constexpr (VEC == 4) {
            float4 t = *reinterpret_cast<const float4*>(p);
            xs[0] = t.x; xs[1] = t.y; xs[2] = t.z; xs[3] = t.w;
        } else {
            xs[0] = *p;
        }
        cone(c, xs);
    }

#pragma unroll
    for (int ol = 0; ol < OT; ++ol) {
        int o = oBase + ol;
        if (o >= O) continue;
        float sc = ssc[ol], sh = ssh[ol];
        float res[VEC];
#pragma unroll
        for (int j = 0; j < VEC; ++j) {
            float y = acc[ol][j] * sc + sh;
            if (relu) y = fmaxf(y, 0.f);
            res[j] = y;
        }
        float* op = outp + ((size_t)nb * O + o) * N + n0;
        if constexpr (VEC == 4) {
            float4 t; t.x = res[0]; t.y = res[1]; t.z = res[2]; t.w = res[3];
            *reinterpret_cast<float4*>(op) = t;
        } else {
            *op = res[0];
        }
    }
}

extern "C" void kernel_launch(void* const* d_in, const int* in_sizes, int n_in,
                              void* d_out, int out_size, void* d_ws, size_t ws_size,
                              hipStream_t stream) {
    const int B = 2, Q = 16, N0 = 4096, N1 = 1024, N2 = 256;
    const int I1 = 144, I2 = 72, I3 = 36;
    const int NB = B * Q;  // 32

    const float* x     = (const float*)d_in[0];   // (B, 288, N2)
    const float* mask  = (const float*)d_in[1];   // (NB, 8, N2)
    const float* sa0f  = (const float*)d_in[2];   // (B, 3, N0)
    const float* sa1f  = (const float*)d_in[3];   // (B, 128, N1)
    const float* xyz0  = (const float*)d_in[4];   // (B, N0, 3)
    const float* xyz1  = (const float*)d_in[5];   // (B, N1, 3)
    const float* xyz2  = (const float*)d_in[6];   // (B, N2, 3)

    float* ws = (float*)d_ws;
    size_t off = 0;
    auto alloc = [&](size_t n) { size_t p = off; off += (n + 15) & ~(size_t)15; return p; };

    size_t f0b   = alloc((size_t)B * I2 * N0);    // adapter1 out (per-b)
    size_t f1b   = alloc((size_t)B * I1 * N1);    // adapter2 out (per-b)
    size_t wgt1  = alloc((size_t)B * N1 * 3);
    size_t wgt2  = alloc((size_t)B * N0 * 3);
    size_t idx1  = alloc((size_t)B * N1 * 3);
    size_t idx2  = alloc((size_t)B * N0 * 3);
    size_t slotA = alloc((size_t)NB * I2 * N0);   // h1 / interp1 / interp2
    size_t slotB = alloc((size_t)NB * I2 * N0);   // h2 / h3 / h5
    size_t slotC = alloc((size_t)NB * I3 * N0);   // h4 / h6
    (void)ws_size; (void)in_sizes; (void)n_in;

    // vec=4 for N>=1024 big layers (float4/lane, OT=16);
    // vec=1 for N=256 layers and adapters (OT=32).
    auto conv = [&](const float* s0, int C0, int q0, const float* s1, int C1, int q1,
                    int wi, int bi, int bni, float* outp,
                    int O, int Nn, int nbatch, int relu, int vec) {
        const float* Wp = (const float*)d_in[wi];
        const float* bp = (const float*)d_in[bi];
        const float* np = bni >= 0 ? (const float*)d_in[bni] : nullptr;
        if (vec == 4) {
            dim3 grid(Nn / 1024, (O + 15) / 16, nbatch);
            conv_stream_kernel<4, 16><<<grid, 256, 0, stream>>>(
                s0, C0, q0, s1, C1, q1, Wp, bp, np, outp, O, Nn, relu);
        } else {
            dim3 grid(Nn / 256, (O + 31) / 32, nbatch);
            conv_stream_kernel<1, 32><<<grid, 256, 0, stream>>>(
                s0, C0, q0, s1, C1, q1, Wp, bp, np, outp, O, Nn, relu);
        }
    };

    // adapters (per-b)
    conv(sa0f, 3, 1, nullptr, 0, 1, 13, 14, -1, ws + f0b, I2, N0, B, 0, 1);
    conv(sa1f, 128, 1, nullptr, 0, 1, 15, 16, -1, ws + f1b, I1, N1, B, 0, 1);

    // three_nn (per-b), segment-parallel
    three_nn_par_kernel<<<dim3(N1 / 32, B), dim3(512), 0, stream>>>(
        xyz1, xyz2, N1, N2, (int*)(ws + idx1), ws + wgt1);
    three_nn_par_kernel<<<dim3(N0 / 32, B), dim3(512), 0, stream>>>(
        xyz0, xyz1, N0, N1, (int*)(ws + idx2), ws + wgt2);

    // h1 = layer1(concat(x, mask)) : (NB, 296, 256) -> slotA
    conv(x, 288, Q, mask, 8, 1, 7, 8, 9, ws + slotA, 296, N2, NB, 1, 1);
    // h2 = layer2(h1) : (NB, 144, 256) -> slotB
    conv(ws + slotA, 296, 1, nullptr, 0, 1, 10, 11, 12, ws + slotB, I1, N2, NB, 1, 1);

    // interp1: h2 (Ns=256) -> (NB, 144, 1024) -> slotA
    interp_kernel<<<dim3(N1 / 256, I1, NB), dim3(256), 0, stream>>>(
        ws + slotB, (const int*)(ws + idx1), ws + wgt1, ws + slotA, I1, N2, N1, Q);

    // h3 = fp1_layer1(concat(interp1, f1)) -> slotB
    conv(ws + slotA, I1, 1, ws + f1b, I1, Q, 17, 18, 19, ws + slotB, I1, N1, NB, 1, 4);
    // h4 = fp1_layer2(h3) -> slotC
    conv(ws + slotB, I1, 1, nullptr, 0, 1, 20, 21, 22, ws + slotC, I2, N1, NB, 1, 4);

    // interp2: h4 (Ns=1024) -> (NB, 72, 4096) -> slotA
    interp_kernel<<<dim3(N0 / 256, I2, NB), dim3(256), 0, stream>>>(
        ws + slotC, (const int*)(ws + idx2), ws + wgt2, ws + slotA, I2, N1, N0, Q);

    // h5 = fp2_layer1(concat(interp2, f0)) -> slotB
    conv(ws + slotA, I2, 1, ws + f0b, I2, Q, 23, 24, 25, ws + slotB, I2, N0, NB, 1, 4);
    // h6 = fp2_layer2(h5) -> slotC
    conv(ws + slotB, I2, 1, nullptr, 0, 1, 26, 27, 28, ws + slotC, I3, N0, NB, 1, 4);

    // out = out_w @ h6 + out_b -> d_out (fp32)
    conv(ws + slotC, I3, 1, nullptr, 0, 1, 29, 30, -1, (float*)d_out, 1, N0, NB, 0, 4);
}

// Round 5
// 404.582 us; speedup vs baseline: 1.1449x; 1.1449x over previous
//
#include <hip/hip_runtime.h>

#define EPS_BN 1e-5f

// ---------------- three_nn (unchanged, verified r3) ----------------
__global__ __launch_bounds__(512) void three_nn_par_kernel(
    const float* __restrict__ unknown,  // (B, Nu, 3)
    const float* __restrict__ known,    // (B, Nk, 3)
    int Nu, int Nk, int* __restrict__ idx, float* __restrict__ wgt)
{
    const int NSEG = 16;
    __shared__ float kl[3 * 1024];
    __shared__ float sd[NSEG][32][3];
    __shared__ int   si[NSEG][32][3];
    const int b = blockIdx.y;
    for (int i = threadIdx.x; i < Nk * 3; i += 512) kl[i] = known[(size_t)b * Nk * 3 + i];
    __syncthreads();
    const int u   = threadIdx.x & 31;
    const int seg = threadIdx.x >> 5;
    const int n   = blockIdx.x * 32 + u;
    const float* up = unknown + ((size_t)b * Nu + n) * 3;
    const float ux = up[0], uy = up[1], uz = up[2];
    float d0 = 1e30f, d1 = 1e30f, d2 = 1e30f;
    int i0 = 0, i1 = 0, i2 = 0;
    const int klo = seg * (Nk / NSEG), khi = klo + Nk / NSEG;
    for (int k = klo; k < khi; ++k) {
        float dx = __fsub_rn(ux, kl[3 * k + 0]);
        float dy = __fsub_rn(uy, kl[3 * k + 1]);
        float dz = __fsub_rn(uz, kl[3 * k + 2]);
        float d = __fadd_rn(__fadd_rn(__fmul_rn(dx, dx), __fmul_rn(dy, dy)), __fmul_rn(dz, dz));
        if (d < d0)      { d2 = d1; i2 = i1; d1 = d0; i1 = i0; d0 = d; i0 = k; }
        else if (d < d1) { d2 = d1; i2 = i1; d1 = d;  i1 = k; }
        else if (d < d2) { d2 = d;  i2 = k; }
    }
    sd[seg][u][0] = d0; sd[seg][u][1] = d1; sd[seg][u][2] = d2;
    si[seg][u][0] = i0; si[seg][u][1] = i1; si[seg][u][2] = i2;
    __syncthreads();
    if (threadIdx.x < 32) {
        float m0 = 1e30f, m1 = 1e30f, m2 = 1e30f;
        int j0 = 0, j1 = 0, j2 = 0;
        for (int s = 0; s < NSEG; ++s)
            for (int c = 0; c < 3; ++c) {
                float d = sd[s][u][c];
                int ii = si[s][u][c];
                if (d < m0)      { m2 = m1; j2 = j1; m1 = m0; j1 = j0; m0 = d; j0 = ii; }
                else if (d < m1) { m2 = m1; j2 = j1; m1 = d;  j1 = ii; }
                else if (d < m2) { m2 = d;  j2 = ii; }
            }
        float w0 = 1.f / (m0 + 1e-8f), w1 = 1.f / (m1 + 1e-8f), w2 = 1.f / (m2 + 1e-8f);
        float s = w0 + w1 + w2;
        size_t base = ((size_t)b * Nu + n) * 3;
        idx[base + 0] = j0; idx[base + 1] = j1; idx[base + 2] = j2;
        wgt[base + 0] = w0 / s; wgt[base + 1] = w1 / s; wgt[base + 2] = w2 / s;
    }
}

// ---------------- interp: c-loop inside, idx/wgt loaded once ----------------
__global__ __launch_bounds__(256) void interp_kernel(
    const float* __restrict__ feat,                              // (NB, C, Ns)
    const int* __restrict__ idx, const float* __restrict__ wgt,  // (B, Nu, 3)
    float* __restrict__ out,                                     // (NB, C, Nu)
    int C, int Ns, int Nu, int Q)
{
    int n = blockIdx.x * 256 + threadIdx.x;
    int nb = blockIdx.y;
    int b = nb / Q;
    size_t nnb = ((size_t)b * Nu + n) * 3;
    int j0 = idx[nnb], j1 = idx[nnb + 1], j2 = idx[nnb + 2];
    float w0 = wgt[nnb], w1 = wgt[nnb + 1], w2 = wgt[nnb + 2];
    const float* f = feat + (size_t)nb * C * Ns;
    float* op = out + (size_t)nb * C * Nu + n;
#pragma unroll 4
    for (int c = 0; c < C; ++c) {
        const float* fr = f + (size_t)c * Ns;
        op[(size_t)c * Nu] = w0 * fr[j0] + w1 * fr[j1] + w2 * fr[j2];
    }
}

// ---------------- weight prep: transpose + fold BN scale ----------------
struct LayerDesc {
    const float* W; const float* b; const float* bn;
    float* wt; float* shb; int O; int C;
};
struct PrepArgs { LayerDesc l[9]; };

__global__ __launch_bounds__(256) void prep_kernel(PrepArgs a) {
    LayerDesc d = a.l[blockIdx.y];
    int total = d.O * d.C;
    for (int i = blockIdx.x * 256 + threadIdx.x; i < total; i += gridDim.x * 256) {
        int c = i / d.O, o = i - (i / d.O) * d.O;
        float sc = 1.f;
        if (d.bn) { float g = d.bn[o], v = d.bn[3 * d.O + o]; sc = g * rsqrtf(v + EPS_BN); }
        d.wt[i] = d.W[(size_t)o * d.C + c] * sc;
    }
    for (int o = blockIdx.x * 256 + threadIdx.x; o < d.O; o += gridDim.x * 256) {
        float sc = 1.f, sh = 0.f;
        if (d.bn) {
            float g = d.bn[o], be = d.bn[d.O + o], m = d.bn[2 * d.O + o], v = d.bn[3 * d.O + o];
            sc = g * rsqrtf(v + EPS_BN); sh = be - m * sc;
        }
        d.shb[o] = d.b[o] * sc + sh;
    }
}

// ---------------- conv: compile-time shapes, barrier-free, scalar weights ----
// y = relu( sum_c Wt[c][o] * x[c][n] + shb[o] )   (BN scale pre-folded into Wt)
template <int C0, int C1, int O, int OT, int VEC, bool RELU>
__global__ __launch_bounds__(256) void conv_tpl(
    const float* __restrict__ src0, int qdiv0,
    const float* __restrict__ src1, int qdiv1,
    const float* __restrict__ Wt,   // [C0+C1][O]
    const float* __restrict__ shb,  // [O]
    float* __restrict__ outp, int N)
{
    constexpr int CT = C0 + C1;
    const int tid = threadIdx.x;
    const int oBase = blockIdx.y * OT;
    const int nb = blockIdx.z;
    const int n0 = (blockIdx.x * 256 + tid) * VEC;

    const float* s0 = src0 + (size_t)(nb / qdiv0) * C0 * N + n0;
    const float* s1 = (C1 > 0) ? (src1 + (size_t)(nb / qdiv1) * C1 * N + n0) : nullptr;

    float acc[OT][VEC];
#pragma unroll
    for (int ol = 0; ol < OT; ++ol)
#pragma unroll
        for (int j = 0; j < VEC; ++j) acc[ol][j] = 0.f;

    auto rowp = [&](int c) -> const float* {
        if constexpr (C1 == 0) return s0 + (size_t)c * N;
        else return (c < C0) ? (s0 + (size_t)c * N) : (s1 + (size_t)(c - C0) * N);
    };
    auto loadrow = [&](float (&x)[VEC], int c) {
        const float* p = rowp(c);
        if constexpr (VEC == 4) {
            float4 t = *reinterpret_cast<const float4*>(p);
            x[0] = t.x; x[1] = t.y; x[2] = t.z; x[3] = t.w;
        } else if constexpr (VEC == 2) {
            float2 t = *reinterpret_cast<const float2*>(p);
            x[0] = t.x; x[1] = t.y;
        } else {
            x[0] = *p;
        }
    };
    auto comprow = [&](const float (&x)[VEC], int c) {
        const float* wr = Wt + (size_t)c * O + oBase;   // wave-uniform -> s_load
#pragma unroll
        for (int ol = 0; ol < OT; ++ol) {
            float w = wr[ol];
#pragma unroll
            for (int j = 0; j < VEC; ++j) acc[ol][j] += w * x[j];
        }
    };
    auto loadg = [&](float (&buf)[4][VEC], int c) {
#pragma unroll
        for (int q = 0; q < 4; ++q) loadrow(buf[q], c + q);
    };
    auto compg = [&](const float (&buf)[4][VEC], int c) {
#pragma unroll
        for (int q = 0; q < 4; ++q) comprow(buf[q], c + q);
    };

    if constexpr (CT == 3) {
        float xs[3][VEC];
        loadrow(xs[0], 0); loadrow(xs[1], 1); loadrow(xs[2], 2);
        comprow(xs[0], 0); comprow(xs[1], 1); comprow(xs[2], 2);
    } else {
        static_assert(CT % 8 == 0 || CT % 8 == 4, "CT pipeline tail");
        float xa[4][VEC], xb[4][VEC];
        loadg(xa, 0); loadg(xb, 4);
        int c = 0;
#pragma unroll 1
        for (; c + 16 <= CT; c += 8) {
            compg(xa, c);     loadg(xa, c + 8);
            compg(xb, c + 4); loadg(xb, c + 12);
        }
        compg(xa, c);
        if constexpr (CT % 8 == 4) {
            loadg(xa, c + 8);
            compg(xb, c + 4);
            compg(xa, c + 8);
        } else {
            compg(xb, c + 4);
        }
    }

#pragma unroll
    for (int ol = 0; ol < OT; ++ol) {
        int o = oBase + ol;
        float sb = shb[o];
        float res[VEC];
#pragma unroll
        for (int j = 0; j < VEC; ++j) {
            float y = acc[ol][j] + sb;
            if constexpr (RELU) y = fmaxf(y, 0.f);
            res[j] = y;
        }
        float* op = outp + ((size_t)nb * O + o) * N + n0;
        if constexpr (VEC == 4) {
            float4 t; t.x = res[0]; t.y = res[1]; t.z = res[2]; t.w = res[3];
            *reinterpret_cast<float4*>(op) = t;
        } else if constexpr (VEC == 2) {
            float2 t; t.x = res[0]; t.y = res[1];
            *reinterpret_cast<float2*>(op) = t;
        } else {
            *op = res[0];
        }
    }
}

extern "C" void kernel_launch(void* const* d_in, const int* in_sizes, int n_in,
                              void* d_out, int out_size, void* d_ws, size_t ws_size,
                              hipStream_t stream) {
    const int B = 2, Q = 16, N0 = 4096, N1 = 1024, N2 = 256;
    const int I1 = 144, I2 = 72, I3 = 36;
    const int NB = B * Q;  // 32

    const float* x     = (const float*)d_in[0];   // (B, 288, N2)
    const float* mask  = (const float*)d_in[1];   // (NB, 8, N2)
    const float* sa0f  = (const float*)d_in[2];   // (B, 3, N0)
    const float* sa1f  = (const float*)d_in[3];   // (B, 128, N1)
    const float* xyz0  = (const float*)d_in[4];   // (B, N0, 3)
    const float* xyz1  = (const float*)d_in[5];   // (B, N1, 3)
    const float* xyz2  = (const float*)d_in[6];   // (B, N2, 3)

    float* ws = (float*)d_ws;
    size_t off = 0;
    auto alloc = [&](size_t n) { size_t p = off; off += (n + 15) & ~(size_t)15; return p; };

    size_t f0b   = alloc((size_t)B * I2 * N0);
    size_t f1b   = alloc((size_t)B * I1 * N1);
    size_t wgt1  = alloc((size_t)B * N1 * 3);
    size_t wgt2  = alloc((size_t)B * N0 * 3);
    size_t idx1  = alloc((size_t)B * N1 * 3);
    size_t idx2  = alloc((size_t)B * N0 * 3);
    size_t slotA = alloc((size_t)NB * I2 * N0);   // h1 / interp1 / interp2
    size_t slotB = alloc((size_t)NB * I2 * N0);   // h2 / h3 / h5
    size_t slotC = alloc((size_t)NB * I3 * N0);   // h4 / h6
    // transposed, scale-folded weights + fused shift
    size_t wt1 = alloc(296 * 296), sb1 = alloc(296);
    size_t wt2 = alloc(296 * 144), sb2 = alloc(144);
    size_t wt3 = alloc(288 * 144), sb3 = alloc(144);
    size_t wt4 = alloc(144 * 72),  sb4 = alloc(72);
    size_t wt5 = alloc(144 * 72),  sb5 = alloc(72);
    size_t wt6 = alloc(72 * 36),   sb6 = alloc(36);
    size_t wto = alloc(36),        sbo = alloc(16);
    size_t wa1 = alloc(3 * 72),    sa1b = alloc(72);
    size_t wa2 = alloc(128 * 144), sa2b = alloc(144);
    (void)ws_size; (void)in_sizes; (void)n_in;

    const float* DI(int i);
    auto din = [&](int i) { return (const float*)d_in[i]; };

    PrepArgs pa;
    pa.l[0] = { din(7),  din(8),  din(9),  ws + wt1, ws + sb1, 296, 296 };
    pa.l[1] = { din(10), din(11), din(12), ws + wt2, ws + sb2, 144, 296 };
    pa.l[2] = { din(17), din(18), din(19), ws + wt3, ws + sb3, 144, 288 };
    pa.l[3] = { din(20), din(21), din(22), ws + wt4, ws + sb4, 72, 144 };
    pa.l[4] = { din(23), din(24), din(25), ws + wt5, ws + sb5, 72, 144 };
    pa.l[5] = { din(26), din(27), din(28), ws + wt6, ws + sb6, 36, 72 };
    pa.l[6] = { din(29), din(30), nullptr, ws + wto, ws + sbo, 1, 36 };
    pa.l[7] = { din(13), din(14), nullptr, ws + wa1, ws + sa1b, 72, 3 };
    pa.l[8] = { din(15), din(16), nullptr, ws + wa2, ws + sa2b, 144, 128 };
    prep_kernel<<<dim3(16, 9), 256, 0, stream>>>(pa);

    // three_nn (per-b)
    three_nn_par_kernel<<<dim3(N1 / 32, B), dim3(512), 0, stream>>>(
        xyz1, xyz2, N1, N2, (int*)(ws + idx1), ws + wgt1);
    three_nn_par_kernel<<<dim3(N0 / 32, B), dim3(512), 0, stream>>>(
        xyz0, xyz1, N0, N1, (int*)(ws + idx2), ws + wgt2);

    // adapters (per-b)
    conv_tpl<3, 0, 72, 24, 1, false><<<dim3(16, 3, B), 256, 0, stream>>>(
        sa0f, 1, nullptr, 1, ws + wa1, ws + sa1b, ws + f0b, N0);
    conv_tpl<128, 0, 144, 24, 1, false><<<dim3(4, 6, B), 256, 0, stream>>>(
        sa1f, 1, nullptr, 1, ws + wa2, ws + sa2b, ws + f1b, N1);

    // h1 = layer1(concat(x, mask)) : (NB, 296, 256) -> slotA
    conv_tpl<288, 8, 296, 37, 1, true><<<dim3(1, 8, NB), 256, 0, stream>>>(
        x, Q, mask, 1, ws + wt1, ws + sb1, ws + slotA, N2);
    // h2 : (NB, 144, 256) -> slotB
    conv_tpl<296, 0, 144, 18, 1, true><<<dim3(1, 8, NB), 256, 0, stream>>>(
        ws + slotA, 1, nullptr, 1, ws + wt2, ws + sb2, ws + slotB, N2);

    // interp1: h2 (Ns=256) -> (NB, 144, 1024) -> slotA
    interp_kernel<<<dim3(N1 / 256, NB), 256, 0, stream>>>(
        ws + slotB, (const int*)(ws + idx1), ws + wgt1, ws + slotA, I1, N2, N1, Q);

    // h3 = fp1_layer1(concat(interp1, f1)) -> slotB
    conv_tpl<144, 144, 144, 24, 1, true><<<dim3(4, 6, NB), 256, 0, stream>>>(
        ws + slotA, 1, ws + f1b, Q, ws + wt3, ws + sb3, ws + slotB, N1);
    // h4 -> slotC
    conv_tpl<144, 0, 72, 24, 1, true><<<dim3(4, 3, NB), 256, 0, stream>>>(
        ws + slotB, 1, nullptr, 1, ws + wt4, ws + sb4, ws + slotC, N1);

    // interp2: h4 (Ns=1024) -> (NB, 72, 4096) -> slotA
    interp_kernel<<<dim3(N0 / 256, NB), 256, 0, stream>>>(
        ws + slotC, (const int*)(ws + idx2), ws + wgt2, ws + slotA, I2, N1, N0, Q);

    // h5 = fp2_layer1(concat(interp2, f0)) -> slotB
    conv_tpl<72, 72, 72, 36, 1, true><<<dim3(16, 2, NB), 256, 0, stream>>>(
        ws + slotA, 1, ws + f0b, Q, ws + wt5, ws + sb5, ws + slotB, N0);
    // h6 -> slotC
    conv_tpl<72, 0, 36, 36, 1, true><<<dim3(16, 1, NB), 256, 0, stream>>>(
        ws + slotB, 1, nullptr, 1, ws + wt6, ws + sb6, ws + slotC, N0);

    // out = out_w @ h6 + out_b -> d_out (fp32)
    conv_tpl<36, 0, 1, 1, 4, false><<<dim3(4, 1, NB), 256, 0, stream>>>(
        ws + slotC, 1, nullptr, 1, ws + wto, ws + sbo, (float*)d_out, N0);
}

// Round 6
// 324.029 us; speedup vs baseline: 1.4295x; 1.2486x over previous
//
#include <hip/hip_runtime.h>

#define EPS_BN 1e-5f

// ---------------- three_nn (unchanged, verified r3) ----------------
__global__ __launch_bounds__(512) void three_nn_par_kernel(
    const float* __restrict__ unknown,  // (B, Nu, 3)
    const float* __restrict__ known,    // (B, Nk, 3)
    int Nu, int Nk, int* __restrict__ idx, float* __restrict__ wgt)
{
    const int NSEG = 16;
    __shared__ float kl[3 * 1024];
    __shared__ float sd[NSEG][32][3];
    __shared__ int   si[NSEG][32][3];
    const int b = blockIdx.y;
    for (int i = threadIdx.x; i < Nk * 3; i += 512) kl[i] = known[(size_t)b * Nk * 3 + i];
    __syncthreads();
    const int u   = threadIdx.x & 31;
    const int seg = threadIdx.x >> 5;
    const int n   = blockIdx.x * 32 + u;
    const float* up = unknown + ((size_t)b * Nu + n) * 3;
    const float ux = up[0], uy = up[1], uz = up[2];
    float d0 = 1e30f, d1 = 1e30f, d2 = 1e30f;
    int i0 = 0, i1 = 0, i2 = 0;
    const int klo = seg * (Nk / NSEG), khi = klo + Nk / NSEG;
    for (int k = klo; k < khi; ++k) {
        float dx = __fsub_rn(ux, kl[3 * k + 0]);
        float dy = __fsub_rn(uy, kl[3 * k + 1]);
        float dz = __fsub_rn(uz, kl[3 * k + 2]);
        float d = __fadd_rn(__fadd_rn(__fmul_rn(dx, dx), __fmul_rn(dy, dy)), __fmul_rn(dz, dz));
        if (d < d0)      { d2 = d1; i2 = i1; d1 = d0; i1 = i0; d0 = d; i0 = k; }
        else if (d < d1) { d2 = d1; i2 = i1; d1 = d;  i1 = k; }
        else if (d < d2) { d2 = d;  i2 = k; }
    }
    sd[seg][u][0] = d0; sd[seg][u][1] = d1; sd[seg][u][2] = d2;
    si[seg][u][0] = i0; si[seg][u][1] = i1; si[seg][u][2] = i2;
    __syncthreads();
    if (threadIdx.x < 32) {
        float m0 = 1e30f, m1 = 1e30f, m2 = 1e30f;
        int j0 = 0, j1 = 0, j2 = 0;
        for (int s = 0; s < NSEG; ++s)
            for (int c = 0; c < 3; ++c) {
                float d = sd[s][u][c];
                int ii = si[s][u][c];
                if (d < m0)      { m2 = m1; j2 = j1; m1 = m0; j1 = j0; m0 = d; j0 = ii; }
                else if (d < m1) { m2 = m1; j2 = j1; m1 = d;  j1 = ii; }
                else if (d < m2) { m2 = d;  j2 = ii; }
            }
        float w0 = 1.f / (m0 + 1e-8f), w1 = 1.f / (m1 + 1e-8f), w2 = 1.f / (m2 + 1e-8f);
        float s = w0 + w1 + w2;
        size_t base = ((size_t)b * Nu + n) * 3;
        idx[base + 0] = j0; idx[base + 1] = j1; idx[base + 2] = j2;
        wgt[base + 0] = w0 / s; wgt[base + 1] = w1 / s; wgt[base + 2] = w2 / s;
    }
}

// ---------------- interp: c-loop inside, idx/wgt loaded once ----------------
__global__ __launch_bounds__(256) void interp_kernel(
    const float* __restrict__ feat,                              // (NB, C, Ns)
    const int* __restrict__ idx, const float* __restrict__ wgt,  // (B, Nu, 3)
    float* __restrict__ out,                                     // (NB, C, Nu)
    int C, int Ns, int Nu, int Q)
{
    int n = blockIdx.x * 256 + threadIdx.x;
    int nb = blockIdx.y;
    int b = nb / Q;
    size_t nnb = ((size_t)b * Nu + n) * 3;
    int j0 = idx[nnb], j1 = idx[nnb + 1], j2 = idx[nnb + 2];
    float w0 = wgt[nnb], w1 = wgt[nnb + 1], w2 = wgt[nnb + 2];
    const float* f = feat + (size_t)nb * C * Ns;
    float* op = out + (size_t)nb * C * Nu + n;
#pragma unroll 4
    for (int c = 0; c < C; ++c) {
        const float* fr = f + (size_t)c * Ns;
        op[(size_t)c * Nu] = w0 * fr[j0] + w1 * fr[j1] + w2 * fr[j2];
    }
}

// ---------------- weight prep: transpose + fold BN scale ----------------
struct LayerDesc {
    const float* W; const float* b; const float* bn;
    float* wt; float* shb; int O; int C;
};
struct PrepArgs { LayerDesc l[9]; };

__global__ __launch_bounds__(256) void prep_kernel(PrepArgs a) {
    LayerDesc d = a.l[blockIdx.y];
    int total = d.O * d.C;
    for (int i = blockIdx.x * 256 + threadIdx.x; i < total; i += gridDim.x * 256) {
        int c = i / d.O, o = i - (i / d.O) * d.O;
        float sc = 1.f;
        if (d.bn) { float g = d.bn[o], v = d.bn[3 * d.O + o]; sc = g * rsqrtf(v + EPS_BN); }
        d.wt[i] = d.W[(size_t)o * d.C + c] * sc;
    }
    for (int o = blockIdx.x * 256 + threadIdx.x; o < d.O; o += gridDim.x * 256) {
        float sc = 1.f, sh = 0.f;
        if (d.bn) {
            float g = d.bn[o], be = d.bn[d.O + o], m = d.bn[2 * d.O + o], v = d.bn[3 * d.O + o];
            sc = g * rsqrtf(v + EPS_BN); sh = be - m * sc;
        }
        d.shb[o] = d.b[o] * sc + sh;
    }
}

// ---------------- conv: LDS-staged weight slice, barrier-free main loop ----
// y = relu( sum_c Wt[c][o] * x[c][n] + shb[o] )   (BN scale pre-folded in Wt)
// Block: 256 threads, each owns VEC n-points and OT outputs.
// Weight slice [CT][OT] staged to LDS once (one barrier), read as broadcast
// ds_read_b128 in the loop. x streamed from global, 8 rows in flight.
template <int C0, int C1, int O, int OT, int VEC, bool RELU>
__global__ __launch_bounds__(256) void conv_tpl(
    const float* __restrict__ src0, int qdiv0,
    const float* __restrict__ src1, int qdiv1,
    const float* __restrict__ Wt,   // [C0+C1][O]
    const float* __restrict__ shb,  // [O]
    float* __restrict__ outp, int N)
{
    constexpr int CT = C0 + C1;
    __shared__ __align__(16) float wlds[CT * OT];
    const int tid = threadIdx.x;
    const int oBase = blockIdx.y * OT;
    const int nb = blockIdx.z;
    const int n0 = (blockIdx.x * 256 + tid) * VEC;

    for (int i = tid; i < CT * OT; i += 256)
        wlds[i] = Wt[(size_t)(i / OT) * O + oBase + (i % OT)];
    __syncthreads();

    const float* s0 = src0 + (size_t)(nb / qdiv0) * C0 * N + n0;
    const float* s1 = (C1 > 0) ? (src1 + (size_t)(nb / qdiv1) * C1 * N + n0) : nullptr;

    float acc[OT][VEC];
#pragma unroll
    for (int ol = 0; ol < OT; ++ol)
#pragma unroll
        for (int j = 0; j < VEC; ++j) acc[ol][j] = 0.f;

    auto rowp = [&](int c) -> const float* {
        if constexpr (C1 == 0) return s0 + (size_t)c * N;
        else return (c < C0) ? (s0 + (size_t)c * N) : (s1 + (size_t)(c - C0) * N);
    };
    auto loadrow = [&](float (&x)[VEC], int c) {
        const float* p = rowp(c);
        if constexpr (VEC == 4) {
            float4 t = *reinterpret_cast<const float4*>(p);
            x[0] = t.x; x[1] = t.y; x[2] = t.z; x[3] = t.w;
        } else if constexpr (VEC == 2) {
            float2 t = *reinterpret_cast<const float2*>(p);
            x[0] = t.x; x[1] = t.y;
        } else {
            x[0] = *p;
        }
    };
    auto comprow = [&](const float (&x)[VEC], int c) {
        if constexpr (OT >= 4) {
#pragma unroll
            for (int g = 0; g < OT / 4; ++g) {
                float4 wv = *reinterpret_cast<const float4*>(&wlds[c * OT + g * 4]);
                float ww[4] = {wv.x, wv.y, wv.z, wv.w};
#pragma unroll
                for (int r = 0; r < 4; ++r)
#pragma unroll
                    for (int j = 0; j < VEC; ++j)
                        acc[g * 4 + r][j] += ww[r] * x[j];
            }
        } else {
#pragma unroll
            for (int ol = 0; ol < OT; ++ol) {
                float w = wlds[c * OT + ol];
#pragma unroll
                for (int j = 0; j < VEC; ++j) acc[ol][j] += w * x[j];
            }
        }
    };
    auto loadg = [&](float (&buf)[4][VEC], int c) {
#pragma unroll
        for (int q = 0; q < 4; ++q) loadrow(buf[q], c + q);
    };
    auto compg = [&](const float (&buf)[4][VEC], int c) {
#pragma unroll
        for (int q = 0; q < 4; ++q) comprow(buf[q], c + q);
    };

    if constexpr (CT == 3) {
        float xs[3][VEC];
        loadrow(xs[0], 0); loadrow(xs[1], 1); loadrow(xs[2], 2);
        comprow(xs[0], 0); comprow(xs[1], 1); comprow(xs[2], 2);
    } else {
        static_assert(CT % 8 == 0 || CT % 8 == 4, "CT pipeline tail");
        float xa[4][VEC], xb[4][VEC];
        loadg(xa, 0); loadg(xb, 4);
        int c = 0;
#pragma unroll 1
        for (; c + 16 <= CT; c += 8) {
            compg(xa, c);     loadg(xa, c + 8);
            compg(xb, c + 4); loadg(xb, c + 12);
        }
        compg(xa, c);
        if constexpr (CT % 8 == 4) {
            loadg(xa, c + 8);
            compg(xb, c + 4);
            compg(xa, c + 8);
        } else {
            compg(xb, c + 4);
        }
    }

#pragma unroll
    for (int ol = 0; ol < OT; ++ol) {
        int o = oBase + ol;
        float sb = shb[o];
        float res[VEC];
#pragma unroll
        for (int j = 0; j < VEC; ++j) {
            float y = acc[ol][j] + sb;
            if constexpr (RELU) y = fmaxf(y, 0.f);
            res[j] = y;
        }
        float* op = outp + ((size_t)nb * O + o) * N + n0;
        if constexpr (VEC == 4) {
            float4 t; t.x = res[0]; t.y = res[1]; t.z = res[2]; t.w = res[3];
            *reinterpret_cast<float4*>(op) = t;
        } else if constexpr (VEC == 2) {
            float2 t; t.x = res[0]; t.y = res[1];
            *reinterpret_cast<float2*>(op) = t;
        } else {
            *op = res[0];
        }
    }
}

extern "C" void kernel_launch(void* const* d_in, const int* in_sizes, int n_in,
                              void* d_out, int out_size, void* d_ws, size_t ws_size,
                              hipStream_t stream) {
    const int B = 2, Q = 16, N0 = 4096, N1 = 1024, N2 = 256;
    const int I1 = 144, I2 = 72, I3 = 36;
    const int NB = B * Q;  // 32

    const float* x     = (const float*)d_in[0];   // (B, 288, N2)
    const float* mask  = (const float*)d_in[1];   // (NB, 8, N2)
    const float* sa0f  = (const float*)d_in[2];   // (B, 3, N0)
    const float* sa1f  = (const float*)d_in[3];   // (B, 128, N1)
    const float* xyz0  = (const float*)d_in[4];   // (B, N0, 3)
    const float* xyz1  = (const float*)d_in[5];   // (B, N1, 3)
    const float* xyz2  = (const float*)d_in[6];   // (B, N2, 3)

    float* ws = (float*)d_ws;
    size_t off = 0;
    auto alloc = [&](size_t n) { size_t p = off; off += (n + 15) & ~(size_t)15; return p; };

    size_t f0b   = alloc((size_t)B * I2 * N0);
    size_t f1b   = alloc((size_t)B * I1 * N1);
    size_t wgt1  = alloc((size_t)B * N1 * 3);
    size_t wgt2  = alloc((size_t)B * N0 * 3);
    size_t idx1  = alloc((size_t)B * N1 * 3);
    size_t idx2  = alloc((size_t)B * N0 * 3);
    size_t slotA = alloc((size_t)NB * I2 * N0);   // h1 / interp1 / interp2
    size_t slotB = alloc((size_t)NB * I2 * N0);   // h2 / h3 / h5
    size_t slotC = alloc((size_t)NB * I3 * N0);   // h4 / h6
    size_t wt1 = alloc(296 * 296), sb1 = alloc(296);
    size_t wt2 = alloc(296 * 144), sb2 = alloc(144);
    size_t wt3 = alloc(288 * 144), sb3 = alloc(144);
    size_t wt4 = alloc(144 * 72),  sb4 = alloc(72);
    size_t wt5 = alloc(144 * 72),  sb5 = alloc(72);
    size_t wt6 = alloc(72 * 36),   sb6 = alloc(36);
    size_t wto = alloc(36),        sbo = alloc(16);
    size_t wa1 = alloc(3 * 72),    sa1b = alloc(72);
    size_t wa2 = alloc(128 * 144), sa2b = alloc(144);
    (void)ws_size; (void)in_sizes; (void)n_in;

    auto din = [&](int i) { return (const float*)d_in[i]; };

    PrepArgs pa;
    pa.l[0] = { din(7),  din(8),  din(9),  ws + wt1, ws + sb1, 296, 296 };
    pa.l[1] = { din(10), din(11), din(12), ws + wt2, ws + sb2, 144, 296 };
    pa.l[2] = { din(17), din(18), din(19), ws + wt3, ws + sb3, 144, 288 };
    pa.l[3] = { din(20), din(21), din(22), ws + wt4, ws + sb4, 72, 144 };
    pa.l[4] = { din(23), din(24), din(25), ws + wt5, ws + sb5, 72, 144 };
    pa.l[5] = { din(26), din(27), din(28), ws + wt6, ws + sb6, 36, 72 };
    pa.l[6] = { din(29), din(30), nullptr, ws + wto, ws + sbo, 1, 36 };
    pa.l[7] = { din(13), din(14), nullptr, ws + wa1, ws + sa1b, 72, 3 };
    pa.l[8] = { din(15), din(16), nullptr, ws + wa2, ws + sa2b, 144, 128 };
    prep_kernel<<<dim3(16, 9), 256, 0, stream>>>(pa);

    // three_nn (per-b)
    three_nn_par_kernel<<<dim3(N1 / 32, B), dim3(512), 0, stream>>>(
        xyz1, xyz2, N1, N2, (int*)(ws + idx1), ws + wgt1);
    three_nn_par_kernel<<<dim3(N0 / 32, B), dim3(512), 0, stream>>>(
        xyz0, xyz1, N0, N1, (int*)(ws + idx2), ws + wgt2);

    // adapters (per-b)
    conv_tpl<3, 0, 72, 12, 4, false><<<dim3(4, 6, B), 256, 0, stream>>>(
        sa0f, 1, nullptr, 1, ws + wa1, ws + sa1b, ws + f0b, N0);
    conv_tpl<128, 0, 144, 8, 1, false><<<dim3(4, 18, B), 256, 0, stream>>>(
        sa1f, 1, nullptr, 1, ws + wa2, ws + sa2b, ws + f1b, N1);

    // h1 = layer1(concat(x, mask)) : (NB, 296, 256) -> slotA   [1184 blocks]
    conv_tpl<288, 8, 296, 8, 1, true><<<dim3(1, 37, NB), 256, 0, stream>>>(
        x, Q, mask, 1, ws + wt1, ws + sb1, ws + slotA, N2);
    // h2 : (NB, 144, 256) -> slotB   [576 blocks]
    conv_tpl<296, 0, 144, 8, 1, true><<<dim3(1, 18, NB), 256, 0, stream>>>(
        ws + slotA, 1, nullptr, 1, ws + wt2, ws + sb2, ws + slotB, N2);

    // interp1: h2 (Ns=256) -> (NB, 144, 1024) -> slotA
    interp_kernel<<<dim3(N1 / 256, NB), 256, 0, stream>>>(
        ws + slotB, (const int*)(ws + idx1), ws + wgt1, ws + slotA, I1, N2, N1, Q);

    // h3 = fp1_layer1(concat(interp1, f1)) -> slotB   [1152 blocks]
    conv_tpl<144, 144, 144, 16, 1, true><<<dim3(4, 9, NB), 256, 0, stream>>>(
        ws + slotA, 1, ws + f1b, Q, ws + wt3, ws + sb3, ws + slotB, N1);
    // h4 -> slotC   [1152 blocks]
    conv_tpl<144, 0, 72, 8, 1, true><<<dim3(4, 9, NB), 256, 0, stream>>>(
        ws + slotB, 1, nullptr, 1, ws + wt4, ws + sb4, ws + slotC, N1);

    // interp2: h4 (Ns=1024) -> (NB, 72, 4096) -> slotA
    interp_kernel<<<dim3(N0 / 256, NB), 256, 0, stream>>>(
        ws + slotC, (const int*)(ws + idx2), ws + wgt2, ws + slotA, I2, N1, N0, Q);

    // h5 = fp2_layer1(concat(interp2, f0)) -> slotB   [768 blocks]
    conv_tpl<72, 72, 72, 12, 4, true><<<dim3(4, 6, NB), 256, 0, stream>>>(
        ws + slotA, 1, ws + f0b, Q, ws + wt5, ws + sb5, ws + slotB, N0);
    // h6 -> slotC   [768 blocks]
    conv_tpl<72, 0, 36, 12, 2, true><<<dim3(8, 3, NB), 256, 0, stream>>>(
        ws + slotB, 1, nullptr, 1, ws + wt6, ws + sb6, ws + slotC, N0);

    // out = out_w @ h6 + out_b -> d_out (fp32)   [128 blocks]
    conv_tpl<36, 0, 1, 1, 4, false><<<dim3(4, 1, NB), 256, 0, stream>>>(
        ws + slotC, 1, nullptr, 1, ws + wto, ws + sbo, (float*)d_out, N0);
}